// Round 3
// baseline (231.646 us; speedup 1.0000x reference)
//
#include <hip/hip_runtime.h>

// out[n,d,b] = unique_weights[indices[n], d] * input_values[n,d,b]
// N=16384, U=1024, D=128, B=16, fp32. Pure streaming elementwise, memory-bound.
// Flat element e -> n = e>>11, d = (e>>4)&127. One float4 = 4 consecutive b
// sharing one weight scalar.
//
// Design: 4 float4s per thread (8192 blocks x 256 thr x 4 = 2^23 f4, no tail).
// Nontemporal ld/st for the streaming in/out (zero reuse; keep L2 for the
// reused weight table). Native ext_vector_type because the nontemporal
// builtins reject HIP's struct-based float4.

typedef float floatx4 __attribute__((ext_vector_type(4)));

#define STRIDE   (2097152)          // 8192 blocks * 256 threads

__global__ __launch_bounds__(256) void diagmul_kernel(
    const floatx4* __restrict__ in,
    const float*   __restrict__ w,
    const int*     __restrict__ idx,
    floatx4*       __restrict__ out)
{
    const int i0 = blockIdx.x * 256 + threadIdx.x;

    int i[4];
    float wv[4];
    floatx4 v[4];

    #pragma unroll
    for (int k = 0; k < 4; ++k) i[k] = i0 + k * STRIDE;

    // weight scalars (L1/L2-resident; 4 adjacent lanes share each address)
    #pragma unroll
    for (int k = 0; k < 4; ++k) {
        const int e = i[k] << 2;
        const int n = e >> 11;          // / (D*B)
        const int d = (e >> 4) & 127;   // (/B) % D
        wv[k] = w[idx[n] * 128 + d];
    }

    // streaming loads, batched for memory-level parallelism
    #pragma unroll
    for (int k = 0; k < 4; ++k) v[k] = __builtin_nontemporal_load(&in[i[k]]);

    #pragma unroll
    for (int k = 0; k < 4; ++k) v[k] *= wv[k];

    #pragma unroll
    for (int k = 0; k < 4; ++k) __builtin_nontemporal_store(v[k], &out[i[k]]);
}

extern "C" void kernel_launch(void* const* d_in, const int* in_sizes, int n_in,
                              void* d_out, int out_size, void* d_ws, size_t ws_size,
                              hipStream_t stream) {
    const floatx4* in  = (const floatx4*)d_in[0];   // input_values [N,D,B] fp32
    const float*   w   = (const float*)  d_in[1];   // unique_weights [U,D] fp32
    const int*     idx = (const int*)    d_in[2];   // indices [N] int32
    floatx4*       out = (floatx4*)      d_out;

    // total f4 = out_size/4 = 8388608; grid covers it exactly (4 f4/thread)
    diagmul_kernel<<<8192, 256, 0, stream>>>(in, w, idx, out);
}

// Round 4
// 222.563 us; speedup vs baseline: 1.0408x; 1.0408x over previous
//
#include <hip/hip_runtime.h>

// out[n,d,b] = unique_weights[indices[n], d] * input_values[n,d,b]
// N=16384, U=1024, D=128, B=16, fp32. Pure streaming elementwise, memory-bound.
// Flat element e -> n = e>>11 (D*B=2048), d = (e>>4)&127. One float4 = 4
// consecutive b values sharing one weight scalar.
//
// Round-3 post-mortem: nontemporal hints + 4x batching regressed ~8us (within
// window noise but no win). Kernel never appears in rocprof top-5 (<80us vs
// ~41us traffic floor at 6.6 TB/s); timed window is dominated by harness
// restore/poison fills. Revert to the simplest best-measured form:
// 1 float4/thread, fully coalesced 16B/lane, weight scalar broadcast from L1
// (one n per wave; 16 distinct w addresses per wave, table is L2-resident).

__global__ __launch_bounds__(256) void diagmul_kernel(
    const float4* __restrict__ in,    // N*D*B/4 float4
    const float*  __restrict__ w,     // U*D
    const int*    __restrict__ idx,   // N (int32)
    float4*       __restrict__ out,
    int total_f4)
{
    int i = blockIdx.x * blockDim.x + threadIdx.x;
    if (i >= total_f4) return;

    int e = i << 2;               // flat element index
    int n = e >> 11;              // / (D*B)
    int d = (e >> 4) & 127;       // (/B) % D

    float wv = w[idx[n] * 128 + d];

    float4 v = in[i];
    v.x *= wv; v.y *= wv; v.z *= wv; v.w *= wv;
    out[i] = v;
}

extern "C" void kernel_launch(void* const* d_in, const int* in_sizes, int n_in,
                              void* d_out, int out_size, void* d_ws, size_t ws_size,
                              hipStream_t stream) {
    const float4* in  = (const float4*)d_in[0];   // input_values [N,D,B] fp32
    const float*  w   = (const float*) d_in[1];   // unique_weights [U,D] fp32
    const int*    idx = (const int*)   d_in[2];   // indices [N] int32
    float4*       out = (float4*)      d_out;

    const int total_f4 = out_size / 4;            // 8,388,608
    const int block = 256;
    const int grid  = (total_f4 + block - 1) / block;

    diagmul_kernel<<<grid, block, 0, stream>>>(in, w, idx, out, total_f4);
}